// Round 2
// baseline (27208.337 us; speedup 1.0000x reference)
//
#include <hip/hip_runtime.h>
#include <cstdint>
#include <math.h>

// Problem constants
#define B_   4
#define T_   2048
#define D_   1024
#define H_   8
#define DK_  128
#define P_   4095   // 2T-1

__device__ inline float bf2f(unsigned short s) {
    return __uint_as_float(((unsigned int)s) << 16);
}
__device__ inline unsigned short f2bf(float f) {
    unsigned int u = __float_as_uint(f);
    u += 0x7fffu + ((u >> 16) & 1u);   // round-to-nearest-even
    return (unsigned short)(u >> 16);
}

// Load 8 consecutive EXTERNAL-input elements (element index idx) as fp32.
// MODE 0: input is bf16.  MODE 1: input is fp32.
template <int MODE>
__device__ inline void load8(const void* p, size_t idx, float* o) {
    if (MODE == 0) {
        uint4 v = *(const uint4*)((const unsigned short*)p + idx);
        const unsigned short* s = (const unsigned short*)&v;
#pragma unroll
        for (int j = 0; j < 8; ++j) o[j] = bf2f(s[j]);
    } else {
        const float* f = (const float*)p + idx;
        float4 a = *(const float4*)f;
        float4 b = *(const float4*)(f + 4);
        o[0] = a.x; o[1] = a.y; o[2] = a.z; o[3] = a.w;
        o[4] = b.x; o[5] = b.y; o[6] = b.z; o[7] = b.w;
    }
}

// ---------------------------------------------------------------------------
// dtype detector: if x is fp32, its even 16-bit halves are mantissa junk —
// decoded as bf16 they include wild exponents with overwhelming probability.
// If x is bf16, every even ushort is a sane value. flag: 0 = bf16, 1 = fp32.
// ---------------------------------------------------------------------------
__global__ void detect_kernel(const unsigned short* x, int* flag) {
    if (blockIdx.x == 0 && threadIdx.x == 0) {
        int m = 0;
        for (int i = 0; i < 64; ++i) {
            float v = bf2f(x[2 * i]);
            float a = fabsf(v);
            if (!(a == 0.0f || (a > 1e-20f && a < 1e10f))) m = 1;  // wild/NaN -> fp32
        }
        flag[0] = m;
    }
}

// ---------------------------------------------------------------------------
// Input GEMM: C[m,n] = sum_k A[m,k] * W[n,k]; A,W external (MODE dtype),
// C internal ws bf16.  scatter mode 0: [B,H,T,DK]; 1: [H,P,DK].
// ---------------------------------------------------------------------------
#define BM 128
#define BN 128
#define BK 16

template <int MODE>
__global__ __launch_bounds__(256) void gemm_in(
    const int* __restrict__ flag,
    const void* __restrict__ A, const void* __restrict__ W,
    unsigned short* __restrict__ C, int M, int N, int K, int smode)
{
    if (flag[0] != MODE) return;

    __shared__ float As[BK][BM + 4];
    __shared__ float Ws[BK][BN + 4];

    const int tx = threadIdx.x, ty = threadIdx.y;
    const int l = ty * 16 + tx;
    const int m0 = blockIdx.y * BM;
    const int n0 = blockIdx.x * BN;
    const int arow = l >> 1;
    const int acol = (l & 1) * 8;

    float acc[8][8];
#pragma unroll
    for (int i = 0; i < 8; ++i)
#pragma unroll
        for (int j = 0; j < 8; ++j) acc[i][j] = 0.f;

    for (int k0 = 0; k0 < K; k0 += BK) {
        float tmp[8];
        const int gm = m0 + arow;
        if (gm < M) {
            load8<MODE>(A, (size_t)gm * K + k0 + acol, tmp);
#pragma unroll
            for (int j = 0; j < 8; ++j) As[acol + j][arow] = tmp[j];
        } else {
#pragma unroll
            for (int j = 0; j < 8; ++j) As[acol + j][arow] = 0.f;
        }
        const int gn = n0 + arow;
        load8<MODE>(W, (size_t)gn * K + k0 + acol, tmp);
#pragma unroll
        for (int j = 0; j < 8; ++j) Ws[acol + j][arow] = tmp[j];
        __syncthreads();

#pragma unroll
        for (int kk = 0; kk < BK; ++kk) {
            float4 a0 = *(const float4*)&As[kk][ty * 8];
            float4 a1 = *(const float4*)&As[kk][ty * 8 + 4];
            float4 b0 = *(const float4*)&Ws[kk][tx * 8];
            float4 b1 = *(const float4*)&Ws[kk][tx * 8 + 4];
            float av[8] = {a0.x, a0.y, a0.z, a0.w, a1.x, a1.y, a1.z, a1.w};
            float bv[8] = {b0.x, b0.y, b0.z, b0.w, b1.x, b1.y, b1.z, b1.w};
#pragma unroll
            for (int i = 0; i < 8; ++i)
#pragma unroll
                for (int j = 0; j < 8; ++j) acc[i][j] += av[i] * bv[j];
        }
        __syncthreads();
    }

#pragma unroll
    for (int i = 0; i < 8; ++i) {
        const int m = m0 + ty * 8 + i;
        if (m >= M) continue;
#pragma unroll
        for (int j = 0; j < 8; ++j) {
            const int n = n0 + tx * 8 + j;
            size_t idx;
            if (smode == 0) {
                const int b = m >> 11, t = m & (T_ - 1);
                const int h = n >> 7, dk = n & (DK_ - 1);
                idx = (((size_t)(b * H_ + h)) * T_ + t) * DK_ + dk;
            } else {
                const int h = n >> 7, dk = n & (DK_ - 1);
                idx = ((size_t)h * P_ + m) * DK_ + dk;
            }
            C[idx] = f2bf(acc[i][j]);
        }
    }
}

// ---------------------------------------------------------------------------
// Output GEMM: A internal ws bf16 [M,K], W external (MODE), C external (MODE)
// row-major. Non-finite outputs replaced by mode-specific sentinel for
// diagnosis (12345 = bf16 path, 54321 = fp32 path).
// ---------------------------------------------------------------------------
template <int MODE>
__global__ __launch_bounds__(256) void gemm_out(
    const int* __restrict__ flag,
    const unsigned short* __restrict__ A, const void* __restrict__ W,
    void* __restrict__ C, int M, int N, int K)
{
    if (flag[0] != MODE) return;

    __shared__ float As[BK][BM + 4];
    __shared__ float Ws[BK][BN + 4];

    const int tx = threadIdx.x, ty = threadIdx.y;
    const int l = ty * 16 + tx;
    const int m0 = blockIdx.y * BM;
    const int n0 = blockIdx.x * BN;
    const int arow = l >> 1;
    const int acol = (l & 1) * 8;

    float acc[8][8];
#pragma unroll
    for (int i = 0; i < 8; ++i)
#pragma unroll
        for (int j = 0; j < 8; ++j) acc[i][j] = 0.f;

    for (int k0 = 0; k0 < K; k0 += BK) {
        {
            uint4 av = *(const uint4*)(A + (size_t)(m0 + arow) * K + k0 + acol);
            const unsigned short* s = (const unsigned short*)&av;
#pragma unroll
            for (int j = 0; j < 8; ++j) As[acol + j][arow] = bf2f(s[j]);
            float tmp[8];
            load8<MODE>(W, (size_t)(n0 + arow) * K + k0 + acol, tmp);
#pragma unroll
            for (int j = 0; j < 8; ++j) Ws[acol + j][arow] = tmp[j];
        }
        __syncthreads();

#pragma unroll
        for (int kk = 0; kk < BK; ++kk) {
            float4 a0 = *(const float4*)&As[kk][ty * 8];
            float4 a1 = *(const float4*)&As[kk][ty * 8 + 4];
            float4 b0 = *(const float4*)&Ws[kk][tx * 8];
            float4 b1 = *(const float4*)&Ws[kk][tx * 8 + 4];
            float av[8] = {a0.x, a0.y, a0.z, a0.w, a1.x, a1.y, a1.z, a1.w};
            float bv[8] = {b0.x, b0.y, b0.z, b0.w, b1.x, b1.y, b1.z, b1.w};
#pragma unroll
            for (int i = 0; i < 8; ++i)
#pragma unroll
                for (int j = 0; j < 8; ++j) acc[i][j] += av[i] * bv[j];
        }
        __syncthreads();
    }

#pragma unroll
    for (int i = 0; i < 8; ++i) {
        const int m = m0 + ty * 8 + i;
#pragma unroll
        for (int j = 0; j < 8; ++j) {
            const int n = n0 + tx * 8 + j;
            float v = acc[i][j];
            if (!isfinite(v)) v = (MODE == 0) ? 12345.0f : 54321.0f;
            if (MODE == 0) ((unsigned short*)C)[(size_t)m * N + n] = f2bf(v);
            else           ((float*)C)[(size_t)m * N + n] = v;
        }
    }
}

// ---------------------------------------------------------------------------
// Flash attention with rel-shift folded:  score[q,k] =
//   ((q+u)·K[k] + (q+v)·P[k-q+T-1]) / sqrt(DK).  ws tensors are bf16 in both
// modes; only pos_bias_u/v are external (MODE dtype).
// ---------------------------------------------------------------------------
#define QROWS 16
#define KCH   256
#define SCS   264

template <int MODE>
__global__ __launch_bounds__(256) void attn_kernel(
    const int* __restrict__ flag,
    const unsigned short* __restrict__ qg,
    const unsigned short* __restrict__ kgl,
    const unsigned short* __restrict__ vgl,
    const unsigned short* __restrict__ pg,
    const void* __restrict__ ub,
    const void* __restrict__ vb,
    unsigned short* __restrict__ ao)
{
    if (flag[0] != MODE) return;

    __shared__ float qu[QROWS][DK_];
    __shared__ float qv[QROWS][DK_];
    __shared__ float sc[QROWS][SCS];
    __shared__ float red[QROWS][16];
    __shared__ float mst[QROWS], lst[QROWS], alf[QROWS];

    const int tid = threadIdx.x;
    const int r   = tid >> 4;
    const int c16 = tid & 15;
    const int bh  = blockIdx.y;
    const int h   = bh & (H_ - 1);
    const int q0  = blockIdx.x * QROWS;

    {
        const int d0 = c16 * 8;
        uint4 q4 = *(const uint4*)(qg + ((size_t)bh * T_ + q0 + r) * DK_ + d0);
        const unsigned short* qs = (const unsigned short*)&q4;
        float uu[8], vv[8];
        load8<MODE>(ub, (size_t)h * DK_ + d0, uu);
        load8<MODE>(vb, (size_t)h * DK_ + d0, vv);
#pragma unroll
        for (int j = 0; j < 8; ++j) {
            const float qf = bf2f(qs[j]);
            qu[r][d0 + j] = qf + uu[j];
            qv[r][d0 + j] = qf + vv[j];
        }
    }
    if (tid < QROWS) { mst[tid] = -1e30f; lst[tid] = 0.f; }
    float oacc[8];
#pragma unroll
    for (int j = 0; j < 8; ++j) oacc[j] = 0.f;
    __syncthreads();

    const float scale = 0.08838834764831845f;  // 1/sqrt(128)

    for (int kc0 = 0; kc0 < T_; kc0 += KCH) {
        float lmax = -1e30f;
#pragma unroll 1
        for (int cc = 0; cc < 16; ++cc) {
            const int kc   = c16 + cc * 16;
            const int kidx = kc0 + kc;
            const unsigned short* krow = kgl + ((size_t)bh * T_ + kidx) * DK_;
            const int pj = kidx - (q0 + r) + (T_ - 1);
            const unsigned short* prow = pg + ((size_t)h * P_ + pj) * DK_;
            float ac = 0.f, bd = 0.f;
#pragma unroll
            for (int d8 = 0; d8 < DK_; d8 += 8) {
                uint4 k4 = *(const uint4*)(krow + d8);
                uint4 p4 = *(const uint4*)(prow + d8);
                float4 qua = *(const float4*)&qu[r][d8];
                float4 qub = *(const float4*)&qu[r][d8 + 4];
                float4 qva = *(const float4*)&qv[r][d8];
                float4 qvb = *(const float4*)&qv[r][d8 + 4];
                const unsigned short* ks = (const unsigned short*)&k4;
                const unsigned short* ps = (const unsigned short*)&p4;
                ac += qua.x * bf2f(ks[0]); ac += qua.y * bf2f(ks[1]);
                ac += qua.z * bf2f(ks[2]); ac += qua.w * bf2f(ks[3]);
                ac += qub.x * bf2f(ks[4]); ac += qub.y * bf2f(ks[5]);
                ac += qub.z * bf2f(ks[6]); ac += qub.w * bf2f(ks[7]);
                bd += qva.x * bf2f(ps[0]); bd += qva.y * bf2f(ps[1]);
                bd += qva.z * bf2f(ps[2]); bd += qva.w * bf2f(ps[3]);
                bd += qvb.x * bf2f(ps[4]); bd += qvb.y * bf2f(ps[5]);
                bd += qvb.z * bf2f(ps[6]); bd += qvb.w * bf2f(ps[7]);
            }
            const float s = (ac + bd) * scale;
            sc[r][kc] = s;
            lmax = fmaxf(lmax, s);
        }
        red[r][c16] = lmax;
        __syncthreads();
        if (c16 == 0) {
            float mc = red[r][0];
#pragma unroll
            for (int i = 1; i < 16; ++i) mc = fmaxf(mc, red[r][i]);
            const float mo = mst[r];
            const float mn = fmaxf(mo, mc);
            alf[r] = __expf(mo - mn);
            mst[r] = mn;
        }
        __syncthreads();

        const float mn = mst[r];
        float lsum = 0.f;
#pragma unroll 1
        for (int cc = 0; cc < 16; ++cc) {
            const int kc = c16 + cc * 16;
            const float e = __expf(sc[r][kc] - mn);
            sc[r][kc] = e;
            lsum += e;
        }
        red[r][c16] = lsum;
        __syncthreads();
        if (c16 == 0) {
            float s = 0.f;
#pragma unroll
            for (int i = 0; i < 16; ++i) s += red[r][i];
            lst[r] = lst[r] * alf[r] + s;
        }

        const float al = alf[r];
#pragma unroll
        for (int j = 0; j < 8; ++j) oacc[j] *= al;
        const unsigned short* vbase = vgl + ((size_t)bh * T_ + kc0) * DK_ + c16 * 8;
#pragma unroll 1
        for (int kc = 0; kc < KCH; ++kc) {
            const float w = sc[r][kc];
            uint4 v4 = *(const uint4*)(vbase + (size_t)kc * DK_);
            const unsigned short* vs = (const unsigned short*)&v4;
#pragma unroll
            for (int j = 0; j < 8; ++j) oacc[j] += w * bf2f(vs[j]);
        }
        __syncthreads();
    }

    const float invl = 1.0f / lst[r];
    unsigned short* orow =
        ao + ((size_t)((bh >> 3) * T_ + q0 + r)) * D_ + h * DK_ + c16 * 8;
#pragma unroll
    for (int j = 0; j < 8; ++j) orow[j] = f2bf(oacc[j] * invl);
}

// ---------------------------------------------------------------------------
extern "C" void kernel_launch(void* const* d_in, const int* in_sizes, int n_in,
                              void* d_out, int out_size, void* d_ws, size_t ws_size,
                              hipStream_t stream) {
    const void* x  = d_in[0];
    const void* pe = d_in[1];
    const void* Wq = d_in[2];
    const void* Wk = d_in[3];
    const void* Wv = d_in[4];
    const void* Wo = d_in[5];
    const void* Wp = d_in[6];
    const void* ub = d_in[7];
    const void* vb = d_in[8];

    int* flag = (int*)d_ws;
    unsigned short* buf = (unsigned short*)d_ws + 16;   // 32-byte offset
    const size_t qkv_n = (size_t)B_ * H_ * T_ * DK_;
    unsigned short* q_ws  = buf;
    unsigned short* k_ws  = q_ws + qkv_n;
    unsigned short* v_ws  = k_ws + qkv_n;
    unsigned short* p_ws  = v_ws + qkv_n;
    unsigned short* ao_ws = p_ws + (size_t)H_ * P_ * DK_;

    detect_kernel<<<1, 64, 0, stream>>>((const unsigned short*)x, flag);

    dim3 blk(16, 16);
    const int M = B_ * T_;
    const dim3 gQKV(D_ / BN, M / BM);
    const dim3 gP(D_ / BN, (P_ + BM - 1) / BM);

    gemm_in<0><<<gQKV, blk, 0, stream>>>(flag, x,  Wq, q_ws, M,  D_, D_, 0);
    gemm_in<1><<<gQKV, blk, 0, stream>>>(flag, x,  Wq, q_ws, M,  D_, D_, 0);
    gemm_in<0><<<gQKV, blk, 0, stream>>>(flag, x,  Wk, k_ws, M,  D_, D_, 0);
    gemm_in<1><<<gQKV, blk, 0, stream>>>(flag, x,  Wk, k_ws, M,  D_, D_, 0);
    gemm_in<0><<<gQKV, blk, 0, stream>>>(flag, x,  Wv, v_ws, M,  D_, D_, 0);
    gemm_in<1><<<gQKV, blk, 0, stream>>>(flag, x,  Wv, v_ws, M,  D_, D_, 0);
    gemm_in<0><<<gP,   blk, 0, stream>>>(flag, pe, Wp, p_ws, P_, D_, D_, 1);
    gemm_in<1><<<gP,   blk, 0, stream>>>(flag, pe, Wp, p_ws, P_, D_, D_, 1);

    const dim3 gA(T_ / QROWS, B_ * H_);
    attn_kernel<0><<<gA, dim3(256), 0, stream>>>(flag, q_ws, k_ws, v_ws, p_ws, ub, vb, ao_ws);
    attn_kernel<1><<<gA, dim3(256), 0, stream>>>(flag, q_ws, k_ws, v_ws, p_ws, ub, vb, ao_ws);

    gemm_out<0><<<gQKV, blk, 0, stream>>>(flag, ao_ws, Wo, d_out, M, D_, D_);
    gemm_out<1><<<gQKV, blk, 0, stream>>>(flag, ao_ws, Wo, d_out, M, D_, D_);
}

// Round 3
// 2065.114 us; speedup vs baseline: 13.1752x; 13.1752x over previous
//
#include <hip/hip_runtime.h>
#include <cstdint>
#include <math.h>

// Problem constants
#define B_   4
#define T_   2048
#define D_   1024
#define H_   8
#define DK_  128
#define P_   4095   // 2T-1
#define PS_  4096   // padded P rows per head (row 4095 = poison, never consumed)

typedef __attribute__((ext_vector_type(8))) short short8;
typedef __attribute__((ext_vector_type(4))) float floatx4;

__device__ inline float bf2f(unsigned short s) {
    return __uint_as_float(((unsigned int)s) << 16);
}
__device__ inline unsigned short f2bf(float f) {
    unsigned int u = __float_as_uint(f);
    u += 0x7fffu + ((u >> 16) & 1u);   // round-to-nearest-even
    return (unsigned short)(u >> 16);
}

// Load 8 consecutive EXTERNAL-input elements as fp32. MODE 0: bf16, 1: fp32.
template <int MODE>
__device__ inline void load8(const void* p, size_t idx, float* o) {
    if (MODE == 0) {
        uint4 v = *(const uint4*)((const unsigned short*)p + idx);
        const unsigned short* s = (const unsigned short*)&v;
#pragma unroll
        for (int j = 0; j < 8; ++j) o[j] = bf2f(s[j]);
    } else {
        const float* f = (const float*)p + idx;
        float4 a = *(const float4*)f;
        float4 b = *(const float4*)(f + 4);
        o[0] = a.x; o[1] = a.y; o[2] = a.z; o[3] = a.w;
        o[4] = b.x; o[5] = b.y; o[6] = b.z; o[7] = b.w;
    }
}

// dtype detector: flag 0 = bf16 inputs, 1 = fp32 inputs.
__global__ void detect_kernel(const unsigned short* x, int* flag) {
    if (blockIdx.x == 0 && threadIdx.x == 0) {
        int m = 0;
        for (int i = 0; i < 64; ++i) {
            float v = bf2f(x[2 * i]);
            float a = fabsf(v);
            if (!(a == 0.0f || (a > 1e-20f && a < 1e10f))) m = 1;
        }
        flag[0] = m;
    }
}

// ---------------------------------------------------------------------------
// Input GEMM: C[m,n] = sum_k A[m,k]*W[n,k]; A,W external (MODE), C ws bf16.
// smode 0: [B,H,T,DK]; 1: P [H,PS_,DK]; 2: V transposed [B,H,DK,T].
// ---------------------------------------------------------------------------
#define BM 128
#define BN 128
#define BK 16

template <int MODE>
__global__ __launch_bounds__(256) void gemm_in(
    const int* __restrict__ flag,
    const void* __restrict__ A, const void* __restrict__ W,
    unsigned short* __restrict__ C, int M, int N, int K, int smode)
{
    if (flag[0] != MODE) return;

    __shared__ float As[BK][BM + 4];
    __shared__ float Ws[BK][BN + 4];

    const int tx = threadIdx.x, ty = threadIdx.y;
    const int l = ty * 16 + tx;
    const int m0 = blockIdx.y * BM;
    const int n0 = blockIdx.x * BN;
    const int arow = l >> 1;
    const int acol = (l & 1) * 8;

    float acc[8][8];
#pragma unroll
    for (int i = 0; i < 8; ++i)
#pragma unroll
        for (int j = 0; j < 8; ++j) acc[i][j] = 0.f;

    for (int k0 = 0; k0 < K; k0 += BK) {
        float tmp[8];
        const int gm = m0 + arow;
        if (gm < M) {
            load8<MODE>(A, (size_t)gm * K + k0 + acol, tmp);
#pragma unroll
            for (int j = 0; j < 8; ++j) As[acol + j][arow] = tmp[j];
        } else {
#pragma unroll
            for (int j = 0; j < 8; ++j) As[acol + j][arow] = 0.f;
        }
        load8<MODE>(W, (size_t)(n0 + arow) * K + k0 + acol, tmp);
#pragma unroll
        for (int j = 0; j < 8; ++j) Ws[acol + j][arow] = tmp[j];
        __syncthreads();

#pragma unroll
        for (int kk = 0; kk < BK; ++kk) {
            float4 a0 = *(const float4*)&As[kk][ty * 8];
            float4 a1 = *(const float4*)&As[kk][ty * 8 + 4];
            float4 b0 = *(const float4*)&Ws[kk][tx * 8];
            float4 b1 = *(const float4*)&Ws[kk][tx * 8 + 4];
            float av[8] = {a0.x, a0.y, a0.z, a0.w, a1.x, a1.y, a1.z, a1.w};
            float bv[8] = {b0.x, b0.y, b0.z, b0.w, b1.x, b1.y, b1.z, b1.w};
#pragma unroll
            for (int i = 0; i < 8; ++i)
#pragma unroll
                for (int j = 0; j < 8; ++j) acc[i][j] += av[i] * bv[j];
        }
        __syncthreads();
    }

#pragma unroll
    for (int i = 0; i < 8; ++i) {
        const int m = m0 + ty * 8 + i;
        if (m >= M) continue;
#pragma unroll
        for (int j = 0; j < 8; ++j) {
            const int n = n0 + tx * 8 + j;
            size_t idx;
            if (smode == 0) {
                const int b = m >> 11, t = m & (T_ - 1);
                const int h = n >> 7, dk = n & (DK_ - 1);
                idx = (((size_t)(b * H_ + h)) * T_ + t) * DK_ + dk;
            } else if (smode == 1) {
                const int h = n >> 7, dk = n & (DK_ - 1);
                idx = ((size_t)h * PS_ + m) * DK_ + dk;
            } else {
                const int b = m >> 11, t = m & (T_ - 1);
                const int h = n >> 7, dk = n & (DK_ - 1);
                idx = ((size_t)(b * H_ + h) * DK_ + dk) * T_ + t;
            }
            C[idx] = f2bf(acc[i][j]);
        }
    }
}

// ---------------------------------------------------------------------------
// Output GEMM: A ws bf16 [M,K], W external (MODE), C external (MODE) rm.
// ---------------------------------------------------------------------------
template <int MODE>
__global__ __launch_bounds__(256) void gemm_out(
    const int* __restrict__ flag,
    const unsigned short* __restrict__ A, const void* __restrict__ W,
    void* __restrict__ C, int M, int N, int K)
{
    if (flag[0] != MODE) return;

    __shared__ float As[BK][BM + 4];
    __shared__ float Ws[BK][BN + 4];

    const int tx = threadIdx.x, ty = threadIdx.y;
    const int l = ty * 16 + tx;
    const int m0 = blockIdx.y * BM;
    const int n0 = blockIdx.x * BN;
    const int arow = l >> 1;
    const int acol = (l & 1) * 8;

    float acc[8][8];
#pragma unroll
    for (int i = 0; i < 8; ++i)
#pragma unroll
        for (int j = 0; j < 8; ++j) acc[i][j] = 0.f;

    for (int k0 = 0; k0 < K; k0 += BK) {
        {
            uint4 av = *(const uint4*)(A + (size_t)(m0 + arow) * K + k0 + acol);
            const unsigned short* s = (const unsigned short*)&av;
#pragma unroll
            for (int j = 0; j < 8; ++j) As[acol + j][arow] = bf2f(s[j]);
            float tmp[8];
            load8<MODE>(W, (size_t)(n0 + arow) * K + k0 + acol, tmp);
#pragma unroll
            for (int j = 0; j < 8; ++j) Ws[acol + j][arow] = tmp[j];
        }
        __syncthreads();

#pragma unroll
        for (int kk = 0; kk < BK; ++kk) {
            float4 a0 = *(const float4*)&As[kk][ty * 8];
            float4 a1 = *(const float4*)&As[kk][ty * 8 + 4];
            float4 b0 = *(const float4*)&Ws[kk][tx * 8];
            float4 b1 = *(const float4*)&Ws[kk][tx * 8 + 4];
            float av[8] = {a0.x, a0.y, a0.z, a0.w, a1.x, a1.y, a1.z, a1.w};
            float bv[8] = {b0.x, b0.y, b0.z, b0.w, b1.x, b1.y, b1.z, b1.w};
#pragma unroll
            for (int i = 0; i < 8; ++i)
#pragma unroll
                for (int j = 0; j < 8; ++j) acc[i][j] += av[i] * bv[j];
        }
        __syncthreads();
    }

#pragma unroll
    for (int i = 0; i < 8; ++i) {
        const int m = m0 + ty * 8 + i;
#pragma unroll
        for (int j = 0; j < 8; ++j) {
            const int n = n0 + tx * 8 + j;
            float v = acc[i][j];
            if (!isfinite(v)) v = (MODE == 0) ? 12345.0f : 54321.0f;
            if (MODE == 0) ((unsigned short*)C)[(size_t)m * N + n] = f2bf(v);
            else           ((float*)C)[(size_t)m * N + n] = v;
        }
    }
}

// ---------------------------------------------------------------------------
// MFMA flash attention with rel-shift folded.
//   score[q,k] = ((q+u)·K[k] + (q+v)·P[k-q+T-1]) / sqrt(DK)
// Block: 4 waves, each owns 16 q-rows (64 per block). K-chunk = 64.
// Per chunk per wave: AC 16 mfma, BD 20 mfma (80-col band, shift via LDS),
// PV 16 mfma (V pre-transposed [B,H,DK,T]).
// Layouts (m89/m91-verified): A[m=lane&15][k=quad*8+j]; B[k=quad*8+j][n=lane&15];
// C/D: col=lane&15, row=quad*4+reg.
// ---------------------------------------------------------------------------
#define AKC 64

__device__ inline floatx4 mfma16(short8 a, short8 b, floatx4 c) {
    return __builtin_amdgcn_mfma_f32_16x16x32_bf16(a, b, c, 0, 0, 0);
}

template <int MODE>
__global__ __launch_bounds__(256, 3) void attn_mfma(
    const int* __restrict__ flag,
    const unsigned short* __restrict__ qg,
    const unsigned short* __restrict__ kgl,
    const unsigned short* __restrict__ vt,   // [B,H,DK,T]
    const unsigned short* __restrict__ pg,   // [H,PS_,DK]
    const void* __restrict__ ub,
    const void* __restrict__ vb,
    unsigned short* __restrict__ ao)         // [B,T,D]
{
    if (flag[0] != MODE) return;

    __shared__ float bd_lds[4][16][84];                       // band stage
    __shared__ __align__(16) unsigned short pr_lds[4][16][72]; // probs bf16

    const int tid  = threadIdx.x;
    const int w    = tid >> 6;
    const int lane = tid & 63;
    const int r15  = lane & 15;
    const int quad = lane >> 4;
    const int bh   = blockIdx.y;
    const int h    = bh & (H_ - 1);
    const int b    = bh >> 3;
    const int q0w  = blockIdx.x * 64 + w * 16;

    // ---- Q fragments (A-layout) with u/v biases folded, packed bf16 ----
    short8 quA[4], qvA[4];
    {
        const unsigned short* qrow = qg + ((size_t)bh * T_ + q0w + r15) * DK_;
#pragma unroll
        for (int ks = 0; ks < 4; ++ks) {
            const int dk0 = ks * 32 + quad * 8;
            uint4 q4 = *(const uint4*)(qrow + dk0);
            const unsigned short* qs = (const unsigned short*)&q4;
            float uu[8], vv[8];
            load8<MODE>(ub, (size_t)h * DK_ + dk0, uu);
            load8<MODE>(vb, (size_t)h * DK_ + dk0, vv);
#pragma unroll
            for (int j = 0; j < 8; ++j) {
                const float qf = bf2f(qs[j]);
                quA[ks][j] = (short)f2bf(qf + uu[j]);
                qvA[ks][j] = (short)f2bf(qf + vv[j]);
            }
        }
    }

    floatx4 o[8];
    const floatx4 z4 = {0.f, 0.f, 0.f, 0.f};
#pragma unroll
    for (int g = 0; g < 8; ++g) o[g] = z4;
    float mrun[4], lrun[4];
#pragma unroll
    for (int i = 0; i < 4; ++i) { mrun[i] = -1e30f; lrun[i] = 0.f; }

    const float scale = 0.08838834764831845f;  // 1/sqrt(128)

    for (int kc0 = 0; kc0 < T_; kc0 += AKC) {
        // ---- AC = Qu x K^T ----
        floatx4 ac[4];
#pragma unroll
        for (int g = 0; g < 4; ++g) {
            ac[g] = z4;
            const unsigned short* kp =
                kgl + ((size_t)bh * T_ + kc0 + g * 16 + r15) * DK_ + quad * 8;
#pragma unroll
            for (int ks = 0; ks < 4; ++ks)
                ac[g] = mfma16(quA[ks], *(const short8*)(kp + ks * 32), ac[g]);
        }
        // ---- BD band = Qv x P_band^T (80 cols; used 0..78) ----
        const int pbase = kc0 - q0w + (T_ - 1) - 15;
        floatx4 bd[5];
#pragma unroll
        for (int g = 0; g < 5; ++g) {
            bd[g] = z4;
            const unsigned short* pp =
                pg + ((size_t)h * PS_ + pbase + g * 16 + r15) * DK_ + quad * 8;
#pragma unroll
            for (int ks = 0; ks < 4; ++ks)
                bd[g] = mfma16(qvA[ks], *(const short8*)(pp + ks * 32), bd[g]);
        }
#pragma unroll
        for (int g = 0; g < 5; ++g)
#pragma unroll
            for (int i = 0; i < 4; ++i)
                bd_lds[w][quad * 4 + i][g * 16 + r15] = bd[g][i];
        __syncthreads();

        // ---- scores + online softmax (C-layout) ----
        float pr[4][4];   // [g][i]
        float mc[4], alpha[4];
#pragma unroll
        for (int i = 0; i < 4; ++i) {
            const int r = quad * 4 + i;
            float mm = -1e30f;
#pragma unroll
            for (int g = 0; g < 4; ++g) {
                const float s =
                    (ac[g][i] + bd_lds[w][r][g * 16 + r15 - r + 15]) * scale;
                pr[g][i] = s;
                mm = fmaxf(mm, s);
            }
            mc[i] = mm;
        }
#pragma unroll
        for (int i = 0; i < 4; ++i) {
#pragma unroll
            for (int mk = 1; mk < 16; mk <<= 1)
                mc[i] = fmaxf(mc[i], __shfl_xor(mc[i], mk));
            const float mn = fmaxf(mrun[i], mc[i]);
            alpha[i] = __expf(mrun[i] - mn);
            mrun[i] = mn;
            float ls = 0.f;
#pragma unroll
            for (int g = 0; g < 4; ++g) {
                const float e = __expf(pr[g][i] - mn);
                pr[g][i] = e;
                ls += e;
            }
#pragma unroll
            for (int mk = 1; mk < 16; mk <<= 1)
                ls += __shfl_xor(ls, mk);
            lrun[i] = lrun[i] * alpha[i] + ls;
        }
        // rescale O
#pragma unroll
        for (int g = 0; g < 8; ++g)
#pragma unroll
            for (int i = 0; i < 4; ++i) o[g][i] *= alpha[i];
        // probs -> LDS (bf16)
#pragma unroll
        for (int g = 0; g < 4; ++g)
#pragma unroll
            for (int i = 0; i < 4; ++i)
                pr_lds[w][quad * 4 + i][g * 16 + r15] = f2bf(pr[g][i]);
        __syncthreads();

        // ---- PV: probs (A-layout) x V^T ----
        short8 pa[2];
#pragma unroll
        for (int ks2 = 0; ks2 < 2; ++ks2)
            pa[ks2] = *(const short8*)&pr_lds[w][r15][ks2 * 32 + quad * 8];
#pragma unroll
        for (int og = 0; og < 8; ++og) {
            const unsigned short* vp =
                vt + ((size_t)(bh * DK_ + og * 16 + r15)) * T_ + kc0 + quad * 8;
#pragma unroll
            for (int ks2 = 0; ks2 < 2; ++ks2)
                o[og] = mfma16(pa[ks2], *(const short8*)(vp + ks2 * 32), o[og]);
        }
    }

    // ---- epilogue ----
    float inv[4];
#pragma unroll
    for (int i = 0; i < 4; ++i) inv[i] = 1.0f / lrun[i];
#pragma unroll
    for (int og = 0; og < 8; ++og)
#pragma unroll
        for (int i = 0; i < 4; ++i) {
            const size_t idx =
                ((size_t)(b * T_ + q0w + quad * 4 + i)) * D_ + h * DK_ + og * 16 + r15;
            ao[idx] = f2bf(o[og][i] * inv[i]);
        }
}

// ---------------------------------------------------------------------------
extern "C" void kernel_launch(void* const* d_in, const int* in_sizes, int n_in,
                              void* d_out, int out_size, void* d_ws, size_t ws_size,
                              hipStream_t stream) {
    const void* x  = d_in[0];
    const void* pe = d_in[1];
    const void* Wq = d_in[2];
    const void* Wk = d_in[3];
    const void* Wv = d_in[4];
    const void* Wo = d_in[5];
    const void* Wp = d_in[6];
    const void* ub = d_in[7];
    const void* vb = d_in[8];

    int* flag = (int*)d_ws;
    unsigned short* buf = (unsigned short*)d_ws + 16;
    const size_t qkv_n = (size_t)B_ * H_ * T_ * DK_;
    unsigned short* q_ws  = buf;
    unsigned short* k_ws  = q_ws + qkv_n;
    unsigned short* v_ws  = k_ws + qkv_n;                 // [B,H,DK,T]
    unsigned short* p_ws  = v_ws + qkv_n;                 // [H,PS_,DK]
    unsigned short* ao_ws = p_ws + (size_t)H_ * PS_ * DK_;

    detect_kernel<<<1, 64, 0, stream>>>((const unsigned short*)x, flag);

    dim3 blk(16, 16);
    const int M = B_ * T_;
    const dim3 gQKV(D_ / BN, M / BM);
    const dim3 gP(D_ / BN, (P_ + BM - 1) / BM);

    gemm_in<0><<<gQKV, blk, 0, stream>>>(flag, x,  Wq, q_ws, M,  D_, D_, 0);
    gemm_in<1><<<gQKV, blk, 0, stream>>>(flag, x,  Wq, q_ws, M,  D_, D_, 0);
    gemm_in<0><<<gQKV, blk, 0, stream>>>(flag, x,  Wk, k_ws, M,  D_, D_, 0);
    gemm_in<1><<<gQKV, blk, 0, stream>>>(flag, x,  Wk, k_ws, M,  D_, D_, 0);
    gemm_in<0><<<gQKV, blk, 0, stream>>>(flag, x,  Wv, v_ws, M,  D_, D_, 2);
    gemm_in<1><<<gQKV, blk, 0, stream>>>(flag, x,  Wv, v_ws, M,  D_, D_, 2);
    gemm_in<0><<<gP,   blk, 0, stream>>>(flag, pe, Wp, p_ws, P_, D_, D_, 1);
    gemm_in<1><<<gP,   blk, 0, stream>>>(flag, pe, Wp, p_ws, P_, D_, D_, 1);

    const dim3 gA(T_ / 64, B_ * H_);
    attn_mfma<0><<<gA, dim3(256), 0, stream>>>(flag, q_ws, k_ws, v_ws, p_ws, ub, vb, ao_ws);
    attn_mfma<1><<<gA, dim3(256), 0, stream>>>(flag, q_ws, k_ws, v_ws, p_ws, ub, vb, ao_ws);

    gemm_out<0><<<gQKV, blk, 0, stream>>>(flag, ao_ws, Wo, d_out, M, D_, D_);
    gemm_out<1><<<gQKV, blk, 0, stream>>>(flag, ao_ws, Wo, d_out, M, D_, D_);
}

// Round 4
// 683.741 us; speedup vs baseline: 39.7933x; 3.0203x over previous
//
#include <hip/hip_runtime.h>
#include <cstdint>
#include <math.h>

// Problem constants
#define B_   4
#define T_   2048
#define D_   1024
#define H_   8
#define DK_  128
#define P_   4095   // 2T-1
#define PS_  4096   // padded P rows per head (row 4095 = finite junk, never consumed)

typedef unsigned short ushort_t;
typedef __attribute__((ext_vector_type(8))) short short8;
typedef __attribute__((ext_vector_type(4))) float floatx4;

__device__ inline float bf2f(ushort_t s) {
    return __uint_as_float(((unsigned int)s) << 16);
}
__device__ inline ushort_t f2bf(float f) {
    unsigned int u = __float_as_uint(f);
    u += 0x7fffu + ((u >> 16) & 1u);   // round-to-nearest-even
    return (ushort_t)(u >> 16);
}

__device__ inline floatx4 mfma16(short8 a, short8 b, floatx4 c) {
    return __builtin_amdgcn_mfma_f32_16x16x32_bf16(a, b, c, 0, 0, 0);
}

// async global->LDS, 16B per lane; LDS dest = wave-uniform base + lane*16
__device__ inline void gload_lds16(const ushort_t* g, ushort_t* l) {
    __builtin_amdgcn_global_load_lds(
        (const __attribute__((address_space(1))) unsigned int*)g,
        (__attribute__((address_space(3))) unsigned int*)l, 16, 0, 0);
}

// dtype detector: flag 0 = bf16 inputs, 1 = fp32 inputs.
__global__ void detect_kernel(const ushort_t* x, int* flag) {
    if (blockIdx.x == 0 && threadIdx.x == 0) {
        int m = 0;
        for (int i = 0; i < 64; ++i) {
            float v = bf2f(x[2 * i]);
            float a = fabsf(v);
            if (!(a == 0.0f || (a > 1e-20f && a < 1e10f))) m = 1;
        }
        flag[0] = m;
    }
}

// ---------------------------------------------------------------------------
// Conversion: all external tensors -> contiguous bf16 arena.
// Segment source offsets (elements):
//   x 0..8388608, pe ..12581888, Wq ..13630464, Wk ..14679040, Wv ..15727616,
//   Wo ..16776192, Wp ..17824768, ub ..17825792, vb ..17826816
// Dest = i, except segments after pe shift +1024 (peb padded 4095->4096 rows).
// ---------------------------------------------------------------------------
#define CV_TOT 17826816
template <int MODE>
__global__ __launch_bounds__(256) void convert_kernel(
    const int* __restrict__ flag,
    const void* __restrict__ x, const void* __restrict__ pe,
    const void* __restrict__ wq, const void* __restrict__ wk,
    const void* __restrict__ wv, const void* __restrict__ wo,
    const void* __restrict__ wp, const void* __restrict__ ub,
    const void* __restrict__ vb, ushort_t* __restrict__ dst)
{
    if (flag[0] != MODE) return;
    const size_t i = ((size_t)blockIdx.x * 256 + threadIdx.x) * 4;
    if (i >= CV_TOT) return;
    const void* s; size_t off;
    if (i < 8388608)       { s = x;  off = i; }
    else if (i < 12581888) { s = pe; off = i - 8388608; }
    else if (i < 13630464) { s = wq; off = i - 12581888; }
    else if (i < 14679040) { s = wk; off = i - 13630464; }
    else if (i < 15727616) { s = wv; off = i - 14679040; }
    else if (i < 16776192) { s = wo; off = i - 15727616; }
    else if (i < 17824768) { s = wp; off = i - 16776192; }
    else if (i < 17825792) { s = ub; off = i - 17824768; }
    else                   { s = vb; off = i - 17825792; }
    const size_t d = i + (i >= 12581888 ? 1024 : 0);
    if (MODE == 0) {
        *(uint2*)(dst + d) = *(const uint2*)((const ushort_t*)s + off);
    } else {
        float4 f = *(const float4*)((const float*)s + off);
        uint2 o;
        o.x = (unsigned)f2bf(f.x) | ((unsigned)f2bf(f.y) << 16);
        o.y = (unsigned)f2bf(f.z) | ((unsigned)f2bf(f.w) << 16);
        *(uint2*)(dst + d) = o;
    }
}

// ---------------------------------------------------------------------------
// MFMA GEMM: C[m,n] = sum_k A[m,k]*W[n,k], A[M,1024], W[1024,1024] bf16.
// 128x128 tile, BK=32, 4 waves 2x2 (each 64x64 = 4x4 mfma tiles).
// global_load_lds staging with XOR-swizzled 16B slots (slot = c ^ ((row>>1)&3))
// so ds_read_b128 fragments are 2-way bank-aliased (free).
// smode: 0 -> [B,H,T,DK]; 1 -> [H,PS,DK]; 2 -> [B,H,DK,T];
//        3 -> row-major bf16 (runs iff flag==0); 4 -> row-major fp32 (flag==1)
// ---------------------------------------------------------------------------
__global__ __launch_bounds__(256, 3) void gemm_mfma(
    const int* __restrict__ flag,
    const ushort_t* __restrict__ A, const ushort_t* __restrict__ W,
    void* __restrict__ C, int smode)
{
    if (smode == 3 && flag[0] != 0) return;
    if (smode == 4 && flag[0] != 1) return;
    const int K = 1024, N = 1024;

    __shared__ ushort_t Al[128 * 32];
    __shared__ ushort_t Wl[128 * 32];

    const int tid  = threadIdx.x;
    const int w    = tid >> 6, lane = tid & 63;
    const int r15  = lane & 15, quad = lane >> 4;
    const int wm   = w >> 1, wn = w & 1;
    const int m0   = blockIdx.y * 128, n0 = blockIdx.x * 128;

    floatx4 acc[4][4];
    const floatx4 z4 = {0.f, 0.f, 0.f, 0.f};
#pragma unroll
    for (int mt = 0; mt < 4; ++mt)
#pragma unroll
        for (int nt = 0; nt < 4; ++nt) acc[mt][nt] = z4;

    for (int k0 = 0; k0 < K; k0 += 32) {
#pragma unroll
        for (int it = 0; it < 2; ++it) {
            const int rbase = w * 32 + it * 16;
            const int row   = rbase + (lane >> 2);
            const int c     = (lane & 3) ^ ((row >> 1) & 3);
            gload_lds16(A + (size_t)(m0 + row) * K + k0 + c * 8, &Al[rbase * 32]);
            gload_lds16(W + (size_t)(n0 + row) * K + k0 + c * 8, &Wl[rbase * 32]);
        }
        __syncthreads();

        short8 af[4], bf[4];
#pragma unroll
        for (int mt = 0; mt < 4; ++mt) {
            const int row  = wm * 64 + mt * 16 + r15;
            const int slot = quad ^ ((row >> 1) & 3);
            af[mt] = *(const short8*)&Al[row * 32 + slot * 8];
        }
#pragma unroll
        for (int nt = 0; nt < 4; ++nt) {
            const int row  = wn * 64 + nt * 16 + r15;
            const int slot = quad ^ ((row >> 1) & 3);
            bf[nt] = *(const short8*)&Wl[row * 32 + slot * 8];
        }
#pragma unroll
        for (int mt = 0; mt < 4; ++mt)
#pragma unroll
            for (int nt = 0; nt < 4; ++nt)
                acc[mt][nt] = mfma16(af[mt], bf[nt], acc[mt][nt]);
        __syncthreads();
    }

    // epilogue (C-layout: row = quad*4+i, col = r15)
#pragma unroll
    for (int mt = 0; mt < 4; ++mt)
#pragma unroll
        for (int nt = 0; nt < 4; ++nt)
#pragma unroll
            for (int i = 0; i < 4; ++i) {
                const int m = m0 + wm * 64 + mt * 16 + quad * 4 + i;
                const int n = n0 + wn * 64 + nt * 16 + r15;
                const float v = acc[mt][nt][i];
                if (smode == 0) {
                    const int b = m >> 11, t = m & (T_ - 1);
                    const int h = n >> 7, dk = n & (DK_ - 1);
                    ((ushort_t*)C)[(((size_t)(b * H_ + h)) * T_ + t) * DK_ + dk] = f2bf(v);
                } else if (smode == 1) {
                    const int h = n >> 7, dk = n & (DK_ - 1);
                    ((ushort_t*)C)[((size_t)h * PS_ + m) * DK_ + dk] = f2bf(v);
                } else if (smode == 2) {
                    const int b = m >> 11, t = m & (T_ - 1);
                    const int h = n >> 7, dk = n & (DK_ - 1);
                    ((ushort_t*)C)[((size_t)(b * H_ + h) * DK_ + dk) * T_ + t] = f2bf(v);
                } else if (smode == 3) {
                    ((ushort_t*)C)[(size_t)m * N + n] = f2bf(v);
                } else {
                    ((float*)C)[(size_t)m * N + n] = v;
                }
            }
}

// ---------------------------------------------------------------------------
// MFMA flash attention, rel-shift folded:
//   score[q,k] = ((q+u)·K[k] + (q+v)·P[k-q+T-1]) / sqrt(DK)
// 4 waves x 16 q-rows, K-chunk 64. K and V^T staged in LDS (global_load_lds,
// XOR-swizzled slots, shared by all 4 waves); P-band direct global (L2-hot).
// bd/pr LDS regions are wave-private -> no barriers around them.
// ---------------------------------------------------------------------------
__global__ __launch_bounds__(256, 2) void attn_mfma(
    const ushort_t* __restrict__ qg,
    const ushort_t* __restrict__ kgl,
    const ushort_t* __restrict__ vt,   // [B,H,DK,T]
    const ushort_t* __restrict__ pg,   // [H,PS_,DK]
    const ushort_t* __restrict__ ubb,  // bf16 [H,DK]
    const ushort_t* __restrict__ vbb,
    ushort_t* __restrict__ ao)         // [B,T,D]
{
    __shared__ ushort_t K_lds[64 * 128];   // [row][slot], slot = c ^ (row&7)
    __shared__ ushort_t V_lds[128 * 64];   // [dk][slot],  slot = c ^ (dk&7)
    __shared__ float bd_lds[4][16][84];
    __shared__ __align__(16) ushort_t pr_lds[4][16][72];

    const int tid  = threadIdx.x;
    const int w    = tid >> 6;
    const int lane = tid & 63;
    const int r15  = lane & 15;
    const int quad = lane >> 4;
    const int bh   = blockIdx.y;
    const int h    = bh & (H_ - 1);
    const int b    = bh >> 3;
    const int q0w  = blockIdx.x * 64 + w * 16;

    // Q fragments (A-layout) with u/v biases folded
    short8 quA[4], qvA[4];
    {
        const ushort_t* qrow = qg + ((size_t)bh * T_ + q0w + r15) * DK_;
#pragma unroll
        for (int ks = 0; ks < 4; ++ks) {
            const int dk0 = ks * 32 + quad * 8;
            uint4 q4 = *(const uint4*)(qrow + dk0);
            uint4 u4 = *(const uint4*)(ubb + (size_t)h * DK_ + dk0);
            uint4 v4 = *(const uint4*)(vbb + (size_t)h * DK_ + dk0);
            const ushort_t* qs = (const ushort_t*)&q4;
            const ushort_t* us = (const ushort_t*)&u4;
            const ushort_t* vs = (const ushort_t*)&v4;
#pragma unroll
            for (int j = 0; j < 8; ++j) {
                const float qf = bf2f(qs[j]);
                quA[ks][j] = (short)f2bf(qf + bf2f(us[j]));
                qvA[ks][j] = (short)f2bf(qf + bf2f(vs[j]));
            }
        }
    }

    floatx4 o[8];
    const floatx4 z4 = {0.f, 0.f, 0.f, 0.f};
#pragma unroll
    for (int g = 0; g < 8; ++g) o[g] = z4;
    float mrun[4], lrun[4];
#pragma unroll
    for (int i = 0; i < 4; ++i) { mrun[i] = -1e30f; lrun[i] = 0.f; }

    const float scale = 0.08838834764831845f;  // 1/sqrt(128)

    for (int kc0 = 0; kc0 < T_; kc0 += 64) {
        // ---- stage K chunk (64x128, 16KB): wave w -> rows w*16..+16 ----
#pragma unroll
        for (int it = 0; it < 4; ++it) {
            const int rbase = w * 16 + it * 4;
            const int row   = rbase + (lane >> 4);
            const int c     = (lane & 15) ^ (row & 7);
            gload_lds16(kgl + ((size_t)bh * T_ + kc0 + row) * DK_ + c * 8,
                        &K_lds[rbase * 128]);
        }
        // ---- stage V^T chunk (128x64, 16KB): wave w -> dk rows w*32..+32 ----
#pragma unroll
        for (int it = 0; it < 4; ++it) {
            const int rbase = w * 32 + it * 8;
            const int row   = rbase + (lane >> 3);
            const int c     = (lane & 7) ^ (row & 7);
            gload_lds16(vt + ((size_t)(bh * DK_ + row)) * T_ + kc0 + c * 8,
                        &V_lds[rbase * 64]);
        }
        __syncthreads();

        // ---- AC = Qu x K^T (K from LDS) ----
        floatx4 ac[4];
#pragma unroll
        for (int g = 0; g < 4; ++g) {
            ac[g] = z4;
            const int row = g * 16 + r15;
#pragma unroll
            for (int ks = 0; ks < 4; ++ks) {
                const int slot = (ks * 4 + quad) ^ (row & 7);
                ac[g] = mfma16(quA[ks],
                               *(const short8*)&K_lds[row * 128 + slot * 8],
                               ac[g]);
            }
        }

        // ---- BD band = Qv x P_band^T (direct global, 80 rows) ----
        const int pbase = kc0 - q0w + (T_ - 1) - 15;
        floatx4 bd[5];
#pragma unroll
        for (int g = 0; g < 5; ++g) {
            bd[g] = z4;
            const ushort_t* pp =
                pg + ((size_t)h * PS_ + pbase + g * 16 + r15) * DK_ + quad * 8;
#pragma unroll
            for (int ks = 0; ks < 4; ++ks)
                bd[g] = mfma16(qvA[ks], *(const short8*)(pp + ks * 32), bd[g]);
        }
#pragma unroll
        for (int g = 0; g < 5; ++g)
#pragma unroll
            for (int i = 0; i < 4; ++i)
                bd_lds[w][quad * 4 + i][g * 16 + r15] = bd[g][i];
        // wave-private region: no barrier (lgkmcnt ordering suffices)

        // ---- scores + online softmax (C-layout) ----
        float pr[4][4];
        float mc[4], alpha[4];
#pragma unroll
        for (int i = 0; i < 4; ++i) {
            const int r = quad * 4 + i;
            float mm = -1e30f;
#pragma unroll
            for (int g = 0; g < 4; ++g) {
                const float s =
                    (ac[g][i] + bd_lds[w][r][g * 16 + r15 - r + 15]) * scale;
                pr[g][i] = s;
                mm = fmaxf(mm, s);
            }
            mc[i] = mm;
        }
#pragma unroll
        for (int i = 0; i < 4; ++i) {
#pragma unroll
            for (int mk = 1; mk < 16; mk <<= 1)
                mc[i] = fmaxf(mc[i], __shfl_xor(mc[i], mk));
            const float mn = fmaxf(mrun[i], mc[i]);
            alpha[i] = __expf(mrun[i] - mn);
            mrun[i] = mn;
            float ls = 0.f;
#pragma unroll
            for (int g = 0; g < 4; ++g) {
                const float e = __expf(pr[g][i] - mn);
                pr[g][i] = e;
                ls += e;
            }
#pragma unroll
            for (int mk = 1; mk < 16; mk <<= 1)
                ls += __shfl_xor(ls, mk);
            lrun[i] = lrun[i] * alpha[i] + ls;
        }
#pragma unroll
        for (int g = 0; g < 8; ++g)
#pragma unroll
            for (int i = 0; i < 4; ++i) o[g][i] *= alpha[i];
#pragma unroll
        for (int g = 0; g < 4; ++g)
#pragma unroll
            for (int i = 0; i < 4; ++i)
                pr_lds[w][quad * 4 + i][g * 16 + r15] = f2bf(pr[g][i]);
        // wave-private: no barrier

        // ---- PV: probs (A-layout) x V^T (V from LDS) ----
        short8 pa[2];
#pragma unroll
        for (int ks2 = 0; ks2 < 2; ++ks2)
            pa[ks2] = *(const short8*)&pr_lds[w][r15][ks2 * 32 + quad * 8];
#pragma unroll
        for (int og = 0; og < 8; ++og) {
            const int row = og * 16 + r15;
#pragma unroll
            for (int ks2 = 0; ks2 < 2; ++ks2) {
                const int slot = (ks2 * 4 + quad) ^ (row & 7);
                o[og] = mfma16(pa[ks2],
                               *(const short8*)&V_lds[row * 64 + slot * 8],
                               o[og]);
            }
        }
        __syncthreads();   // all waves done with K_lds/V_lds before restage
    }

    // ---- epilogue ----
    float inv[4];
#pragma unroll
    for (int i = 0; i < 4; ++i) inv[i] = 1.0f / lrun[i];
#pragma unroll
    for (int og = 0; og < 8; ++og)
#pragma unroll
        for (int i = 0; i < 4; ++i) {
            const size_t idx =
                ((size_t)(b * T_ + q0w + quad * 4 + i)) * D_ + h * DK_ + og * 16 + r15;
            ao[idx] = f2bf(o[og][i] * inv[i]);
        }
}

// ---------------------------------------------------------------------------
extern "C" void kernel_launch(void* const* d_in, const int* in_sizes, int n_in,
                              void* d_out, int out_size, void* d_ws, size_t ws_size,
                              hipStream_t stream) {
    const void* x  = d_in[0];
    const void* pe = d_in[1];
    const void* Wq = d_in[2];
    const void* Wk = d_in[3];
    const void* Wv = d_in[4];
    const void* Wo = d_in[5];
    const void* Wp = d_in[6];
    const void* ub = d_in[7];
    const void* vb = d_in[8];

    int* flag = (int*)d_ws;
    ushort_t* arena = (ushort_t*)d_ws + 16;   // +32 B
    ushort_t* xb   = arena;                    // 8,388,608   (reused as ao_ws)
    ushort_t* peb  = arena + 8388608;          // 4,194,304 (4096 rows, last = junk)
    ushort_t* wqb  = arena + 12582912;
    ushort_t* wkb  = wqb + 1048576;
    ushort_t* wvb  = wkb + 1048576;
    ushort_t* wob  = wvb + 1048576;
    ushort_t* wpb  = wob + 1048576;
    ushort_t* ubb  = arena + 17825792;
    ushort_t* vbb  = ubb + 1024;
    ushort_t* q_ws  = arena + 17827840;
    ushort_t* k_ws  = q_ws + 8388608;
    ushort_t* vt_ws = k_ws + 8388608;          // [B,H,DK,T]
    ushort_t* p_ws  = vt_ws + 8388608;         // [H,PS_,DK]
    ushort_t* ao_ws = xb;                      // x dead after q/k/v GEMMs

    detect_kernel<<<1, 64, 0, stream>>>((const ushort_t*)x, flag);

    const int cvb = CV_TOT / 4 / 256;          // 17409 exact
    convert_kernel<0><<<cvb, 256, 0, stream>>>(flag, x, pe, Wq, Wk, Wv, Wo, Wp, ub, vb, arena);
    convert_kernel<1><<<cvb, 256, 0, stream>>>(flag, x, pe, Wq, Wk, Wv, Wo, Wp, ub, vb, arena);

    const dim3 gX(8, 64);   // N/128, M/128 for M=8192
    const dim3 gP(8, 32);   // M=4096 (padded)
    gemm_mfma<<<gX, 256, 0, stream>>>(flag, xb,  wqb, q_ws, 0);
    gemm_mfma<<<gX, 256, 0, stream>>>(flag, xb,  wkb, k_ws, 0);
    gemm_mfma<<<gX, 256, 0, stream>>>(flag, xb,  wvb, vt_ws, 2);
    gemm_mfma<<<gP, 256, 0, stream>>>(flag, peb, wpb, p_ws, 1);

    attn_mfma<<<dim3(T_ / 64, B_ * H_), 256, 0, stream>>>(
        q_ws, k_ws, vt_ws, p_ws, ubb, vbb, ao_ws);

    gemm_mfma<<<gX, 256, 0, stream>>>(flag, ao_ws, wob, d_out, 3);
    gemm_mfma<<<gX, 256, 0, stream>>>(flag, ao_ws, wob, d_out, 4);
}

// Round 5
// 589.461 us; speedup vs baseline: 46.1580x; 1.1599x over previous
//
#include <hip/hip_runtime.h>
#include <cstdint>
#include <math.h>

// Problem constants
#define B_   4
#define T_   2048
#define D_   1024
#define H_   8
#define DK_  128
#define P_   4095   // 2T-1
#define PS_  4096   // padded P rows per head (row 4095 = finite junk, never consumed)

typedef unsigned short ushort_t;
typedef __attribute__((ext_vector_type(8))) short short8;
typedef __attribute__((ext_vector_type(4))) float floatx4;

__device__ inline float bf2f(ushort_t s) {
    return __uint_as_float(((unsigned int)s) << 16);
}
__device__ inline ushort_t f2bf(float f) {
    unsigned int u = __float_as_uint(f);
    u += 0x7fffu + ((u >> 16) & 1u);   // round-to-nearest-even
    return (ushort_t)(u >> 16);
}

__device__ inline floatx4 mfma16(short8 a, short8 b, floatx4 c) {
    return __builtin_amdgcn_mfma_f32_16x16x32_bf16(a, b, c, 0, 0, 0);
}

// async global->LDS, 16B per lane; LDS dest = wave-uniform base + lane*16
__device__ inline void gload_lds16(const ushort_t* g, ushort_t* l) {
    __builtin_amdgcn_global_load_lds(
        (const __attribute__((address_space(1))) unsigned int*)g,
        (__attribute__((address_space(3))) unsigned int*)l, 16, 0, 0);
}

// dtype detector: flag 0 = bf16 inputs, 1 = fp32 inputs.
__global__ void detect_kernel(const ushort_t* x, int* flag) {
    if (blockIdx.x == 0 && threadIdx.x == 0) {
        int m = 0;
        for (int i = 0; i < 64; ++i) {
            float v = bf2f(x[2 * i]);
            float a = fabsf(v);
            if (!(a == 0.0f || (a > 1e-20f && a < 1e10f))) m = 1;
        }
        flag[0] = m;
    }
}

// ---------------------------------------------------------------------------
// Conversion: all external tensors -> contiguous bf16 arena (see r4 offsets).
// ---------------------------------------------------------------------------
#define CV_TOT 17826816
template <int MODE>
__global__ __launch_bounds__(256) void convert_kernel(
    const int* __restrict__ flag,
    const void* __restrict__ x, const void* __restrict__ pe,
    const void* __restrict__ wq, const void* __restrict__ wk,
    const void* __restrict__ wv, const void* __restrict__ wo,
    const void* __restrict__ wp, const void* __restrict__ ub,
    const void* __restrict__ vb, ushort_t* __restrict__ dst)
{
    if (flag[0] != MODE) return;
    const size_t i = ((size_t)blockIdx.x * 256 + threadIdx.x) * 4;
    if (i >= CV_TOT) return;
    const void* s; size_t off;
    if (i < 8388608)       { s = x;  off = i; }
    else if (i < 12581888) { s = pe; off = i - 8388608; }
    else if (i < 13630464) { s = wq; off = i - 12581888; }
    else if (i < 14679040) { s = wk; off = i - 13630464; }
    else if (i < 15727616) { s = wv; off = i - 14679040; }
    else if (i < 16776192) { s = wo; off = i - 15727616; }
    else if (i < 17824768) { s = wp; off = i - 16776192; }
    else if (i < 17825792) { s = ub; off = i - 17824768; }
    else                   { s = vb; off = i - 17825792; }
    const size_t d = i + (i >= 12581888 ? 1024 : 0);
    if (MODE == 0) {
        *(uint2*)(dst + d) = *(const uint2*)((const ushort_t*)s + off);
    } else {
        float4 f = *(const float4*)((const float*)s + off);
        uint2 o;
        o.x = (unsigned)f2bf(f.x) | ((unsigned)f2bf(f.y) << 16);
        o.y = (unsigned)f2bf(f.z) | ((unsigned)f2bf(f.w) << 16);
        *(uint2*)(dst + d) = o;
    }
}

// ---------------------------------------------------------------------------
// MFMA GEMM: C[m,n] = sum_k A[m,k]*W[n,k], A[M,1024], W[1024,1024] bf16.
// 128x128 tile, BK=64, 4 waves 2x2 (each 64x64 = 4x4 mfma tiles).
// LDS in FRAGMENT ORDER: tile stored as 16 chunks of 1KB; chunk (mg,ks)
// holds A-frag rows mg*16..+15, k-slice ks*32..+31 with element
// (row=lane&15, k=ks*32+(lane>>4)*8+j) at chunk_base + lane*16B.
// All ds_read_b128 are then base+lane*16 (conflict-free).
// smode: 0 -> [B,H,T,DK]; 1 -> [H,PS,DK]; 2 -> [B,H,DK,T];
//        3 -> row-major bf16 (iff flag==0); 4 -> row-major fp32 (iff flag==1)
// ---------------------------------------------------------------------------
__global__ __launch_bounds__(256, 3) void gemm_mfma(
    const int* __restrict__ flag,
    const ushort_t* __restrict__ A, const ushort_t* __restrict__ W,
    void* __restrict__ C, int smode)
{
    if (smode == 3 && flag[0] != 0) return;
    if (smode == 4 && flag[0] != 1) return;
    const int K = 1024, N = 1024;

    __shared__ ushort_t Al[16 * 512];   // 16 chunks x 512 ushorts (16KB)
    __shared__ ushort_t Wl[16 * 512];

    const int tid  = threadIdx.x;
    const int w    = tid >> 6, lane = tid & 63;
    const int r15  = lane & 15, quad = lane >> 4;
    const int wm   = w >> 1, wn = w & 1;
    const int m0   = blockIdx.y * 128, n0 = blockIdx.x * 128;

    floatx4 acc[4][4];
    const floatx4 z4 = {0.f, 0.f, 0.f, 0.f};
#pragma unroll
    for (int mt = 0; mt < 4; ++mt)
#pragma unroll
        for (int nt = 0; nt < 4; ++nt) acc[mt][nt] = z4;

    for (int k0 = 0; k0 < K; k0 += 64) {
        // stage: wave w stages chunks s = w*4 .. w*4+3 of both tiles
#pragma unroll
        for (int ss = 0; ss < 4; ++ss) {
            const int s  = w * 4 + ss;
            const int mg = s >> 1, ks = s & 1;
            const int row = mg * 16 + r15;
            const int col = k0 + ks * 32 + quad * 8;
            gload_lds16(A + (size_t)(m0 + row) * K + col, &Al[s * 512]);
            gload_lds16(W + (size_t)(n0 + row) * K + col, &Wl[s * 512]);
        }
        __syncthreads();

        short8 af[2][4], bf[2][4];
#pragma unroll
        for (int ks = 0; ks < 2; ++ks) {
#pragma unroll
            for (int mt = 0; mt < 4; ++mt)
                af[ks][mt] = *(const short8*)&Al[(((wm * 4 + mt) * 2 + ks) * 64 + lane) * 8];
#pragma unroll
            for (int nt = 0; nt < 4; ++nt)
                bf[ks][nt] = *(const short8*)&Wl[(((wn * 4 + nt) * 2 + ks) * 64 + lane) * 8];
        }
#pragma unroll
        for (int ks = 0; ks < 2; ++ks)
#pragma unroll
            for (int mt = 0; mt < 4; ++mt)
#pragma unroll
                for (int nt = 0; nt < 4; ++nt)
                    acc[mt][nt] = mfma16(af[ks][mt], bf[ks][nt], acc[mt][nt]);
        __syncthreads();
    }

    // epilogue (C-layout: row = quad*4+i, col = r15)
#pragma unroll
    for (int mt = 0; mt < 4; ++mt)
#pragma unroll
        for (int nt = 0; nt < 4; ++nt)
#pragma unroll
            for (int i = 0; i < 4; ++i) {
                const int m = m0 + wm * 64 + mt * 16 + quad * 4 + i;
                const int n = n0 + wn * 64 + nt * 16 + r15;
                const float v = acc[mt][nt][i];
                if (smode == 0) {
                    const int b = m >> 11, t = m & (T_ - 1);
                    const int h = n >> 7, dk = n & (DK_ - 1);
                    ((ushort_t*)C)[(((size_t)(b * H_ + h)) * T_ + t) * DK_ + dk] = f2bf(v);
                } else if (smode == 1) {
                    const int h = n >> 7, dk = n & (DK_ - 1);
                    ((ushort_t*)C)[((size_t)h * PS_ + m) * DK_ + dk] = f2bf(v);
                } else if (smode == 2) {
                    const int b = m >> 11, t = m & (T_ - 1);
                    const int h = n >> 7, dk = n & (DK_ - 1);
                    ((ushort_t*)C)[((size_t)(b * H_ + h) * DK_ + dk) * T_ + t] = f2bf(v);
                } else if (smode == 3) {
                    ((ushort_t*)C)[(size_t)m * N + n] = f2bf(v);
                } else {
                    ((float*)C)[(size_t)m * N + n] = v;
                }
            }
}

// ---------------------------------------------------------------------------
// MFMA flash attention, rel-shift folded:
//   score[q,k] = ((q+u)·K[k] + (q+v)·P[k-q+T-1]) / sqrt(DK)
// 4 waves x 16 q-rows, K-chunk 64. K (64x128), V^T (128x64) and the block's
// P band union (exactly 128 rows: [kc0-q0blk+1984 .. +127]) staged in LDS in
// FRAGMENT ORDER (all MFMA ds_read_b128 are base+lane*16, conflict-free).
// bd rel-shift gather done with __shfl (C-layout row r needs band col
// g*16 + r15 + 15 - r; source lane = quad*16 + ((r15+15-r)&15), group +c>>4).
// probs C->A transform via per-wave fragment-ordered pr_lds.
// LDS: 16+16+32+8 = 72KB -> 2 blocks/CU.
// ---------------------------------------------------------------------------
__global__ __launch_bounds__(256, 2) void attn_mfma(
    const ushort_t* __restrict__ qg,
    const ushort_t* __restrict__ kgl,
    const ushort_t* __restrict__ vt,   // [B,H,DK,T]
    const ushort_t* __restrict__ pg,   // [H,PS_,DK]
    const ushort_t* __restrict__ ubb,  // bf16 [H,DK]
    const ushort_t* __restrict__ vbb,
    ushort_t* __restrict__ ao)         // [B,T,D]
{
    __shared__ ushort_t K_lds[16 * 512];   // chunks (gk,ks) = gk*4+ks
    __shared__ ushort_t V_lds[16 * 512];   // chunks (og,ks2) = og*2+ks2
    __shared__ ushort_t P_lds[32 * 512];   // chunks (gb,ks) = gb*4+ks
    __shared__ __align__(16) ushort_t pr_lds[4][1024];  // per-wave A-frag tile

    const int tid  = threadIdx.x;
    const int w    = tid >> 6;
    const int lane = tid & 63;
    const int r15  = lane & 15;
    const int quad = lane >> 4;
    const int bh   = blockIdx.y;
    const int h    = bh & (H_ - 1);
    const int b    = bh >> 3;
    const int q0b  = blockIdx.x * 64;
    const int q0w  = q0b + w * 16;

    // Q fragments (A-layout) with u/v biases folded
    short8 quA[4], qvA[4];
    {
        const ushort_t* qrow = qg + ((size_t)bh * T_ + q0w + r15) * DK_;
#pragma unroll
        for (int ks = 0; ks < 4; ++ks) {
            const int dk0 = ks * 32 + quad * 8;
            uint4 q4 = *(const uint4*)(qrow + dk0);
            uint4 u4 = *(const uint4*)(ubb + (size_t)h * DK_ + dk0);
            uint4 v4 = *(const uint4*)(vbb + (size_t)h * DK_ + dk0);
            const ushort_t* qs = (const ushort_t*)&q4;
            const ushort_t* us = (const ushort_t*)&u4;
            const ushort_t* vs = (const ushort_t*)&v4;
#pragma unroll
            for (int j = 0; j < 8; ++j) {
                const float qf = bf2f(qs[j]);
                quA[ks][j] = (short)f2bf(qf + bf2f(us[j]));
                qvA[ks][j] = (short)f2bf(qf + bf2f(vs[j]));
            }
        }
    }

    // rel-shift gather lane sources (wave-static per i)
    int src[4], hi[4];
#pragma unroll
    for (int i = 0; i < 4; ++i) {
        const int c = r15 + 15 - quad * 4 - i;   // in [0,30]
        src[i] = quad * 16 + (c & 15);
        hi[i]  = c >> 4;                          // 0 or 1
    }

    floatx4 o[8];
    const floatx4 z4 = {0.f, 0.f, 0.f, 0.f};
#pragma unroll
    for (int g = 0; g < 8; ++g) o[g] = z4;
    float mrun[4], lrun[4];
#pragma unroll
    for (int i = 0; i < 4; ++i) { mrun[i] = -1e30f; lrun[i] = 0.f; }

    const float scale = 0.08838834764831845f;  // 1/sqrt(128)

    for (int kc0 = 0; kc0 < T_; kc0 += 64) {
        const int pbb = kc0 - q0b + 1984;   // block band base (>=0, +127 <= 4095)

        // ---- stage K (4 chunks/wave), V^T (4), P band (8) ----
#pragma unroll
        for (int ss = 0; ss < 4; ++ss) {
            const int ck = w * 4 + ss;            // (gk,ks) = (w, ss)
            gload_lds16(kgl + ((size_t)bh * T_ + kc0 + w * 16 + r15) * DK_ + ss * 32 + quad * 8,
                        &K_lds[ck * 512]);
            const int cv = w * 4 + ss;            // (og,ks2) = (cv>>1, cv&1)
            const int og = cv >> 1, ks2 = cv & 1;
            gload_lds16(vt + ((size_t)(bh * DK_ + og * 16 + r15)) * T_ + kc0 + ks2 * 32 + quad * 8,
                        &V_lds[cv * 512]);
        }
#pragma unroll
        for (int ss = 0; ss < 8; ++ss) {
            const int cp = w * 8 + ss;            // (gb,ks) = (cp>>2, cp&3)
            const int gb = cp >> 2, ks = cp & 3;
            gload_lds16(pg + ((size_t)h * PS_ + pbb + gb * 16 + r15) * DK_ + ks * 32 + quad * 8,
                        &P_lds[cp * 512]);
        }
        __syncthreads();

        // ---- AC = Qu x K^T ----
        floatx4 ac[4];
#pragma unroll
        for (int g = 0; g < 4; ++g) {
            ac[g] = z4;
#pragma unroll
            for (int ks = 0; ks < 4; ++ks)
                ac[g] = mfma16(quA[ks],
                               *(const short8*)&K_lds[((g * 4 + ks) * 64 + lane) * 8],
                               ac[g]);
        }
        // ---- BD band = Qv x P_band^T (wave window = groups (3-w)..(3-w)+4) ----
        floatx4 bd[5];
#pragma unroll
        for (int g = 0; g < 5; ++g) {
            bd[g] = z4;
            const int gb = (3 - w) + g;
#pragma unroll
            for (int ks = 0; ks < 4; ++ks)
                bd[g] = mfma16(qvA[ks],
                               *(const short8*)&P_lds[((gb * 4 + ks) * 64 + lane) * 8],
                               bd[g]);
        }

        // ---- scores: shift-gather via shfl, then online softmax ----
        float pr[4][4];
        float mc[4], alpha[4];
#pragma unroll
        for (int i = 0; i < 4; ++i) {
            float mm = -1e30f;
#pragma unroll
            for (int g = 0; g < 4; ++g) {
                const float lo = __shfl(bd[g][i],     src[i], 64);
                const float hh = __shfl(bd[g + 1][i], src[i], 64);
                const float s  = (ac[g][i] + (hi[i] ? hh : lo)) * scale;
                pr[g][i] = s;
                mm = fmaxf(mm, s);
            }
            mc[i] = mm;
        }
#pragma unroll
        for (int i = 0; i < 4; ++i) {
#pragma unroll
            for (int mk = 1; mk < 16; mk <<= 1)
                mc[i] = fmaxf(mc[i], __shfl_xor(mc[i], mk));
            const float mn = fmaxf(mrun[i], mc[i]);
            alpha[i] = __expf(mrun[i] - mn);
            mrun[i] = mn;
            float ls = 0.f;
#pragma unroll
            for (int g = 0; g < 4; ++g) {
                const float e = __expf(pr[g][i] - mn);
                pr[g][i] = e;
                ls += e;
            }
#pragma unroll
            for (int mk = 1; mk < 16; mk <<= 1)
                ls += __shfl_xor(ls, mk);
            lrun[i] = lrun[i] * alpha[i] + ls;
        }
#pragma unroll
        for (int g = 0; g < 8; ++g)
#pragma unroll
            for (int i = 0; i < 4; ++i) o[g][i] *= alpha[i];

        // ---- probs C->A via per-wave fragment-ordered LDS ----
        // element (row=quad*4+i, col=g*16+r15): unit (ks2=g>>1, kq=(g&1)*2+(r15>>3))
#pragma unroll
        for (int g = 0; g < 4; ++g) {
            const int unit = (g >> 1) * 4 + (g & 1) * 2 + (r15 >> 3);
#pragma unroll
            for (int i = 0; i < 4; ++i)
                pr_lds[w][(unit * 16 + quad * 4 + i) * 8 + (r15 & 7)] = f2bf(pr[g][i]);
        }
        // wave-private region: compiler lgkmcnt ordering suffices (no barrier)
        short8 pa[2];
#pragma unroll
        for (int ks2 = 0; ks2 < 2; ++ks2)
            pa[ks2] = *(const short8*)&pr_lds[w][(ks2 * 64 + lane) * 8];

        // ---- PV: probs (A-layout) x V^T ----
#pragma unroll
        for (int og = 0; og < 8; ++og)
#pragma unroll
            for (int ks2 = 0; ks2 < 2; ++ks2)
                o[og] = mfma16(pa[ks2],
                               *(const short8*)&V_lds[((og * 2 + ks2) * 64 + lane) * 8],
                               o[og]);
        __syncthreads();   // all waves done with K/V/P before restage
    }

    // ---- epilogue ----
    float inv[4];
#pragma unroll
    for (int i = 0; i < 4; ++i) inv[i] = 1.0f / lrun[i];
#pragma unroll
    for (int og = 0; og < 8; ++og)
#pragma unroll
        for (int i = 0; i < 4; ++i) {
            const size_t idx =
                ((size_t)(b * T_ + q0w + quad * 4 + i)) * D_ + h * DK_ + og * 16 + r15;
            ao[idx] = f2bf(o[og][i] * inv[i]);
        }
}

// ---------------------------------------------------------------------------
extern "C" void kernel_launch(void* const* d_in, const int* in_sizes, int n_in,
                              void* d_out, int out_size, void* d_ws, size_t ws_size,
                              hipStream_t stream) {
    const void* x  = d_in[0];
    const void* pe = d_in[1];
    const void* Wq = d_in[2];
    const void* Wk = d_in[3];
    const void* Wv = d_in[4];
    const void* Wo = d_in[5];
    const void* Wp = d_in[6];
    const void* ub = d_in[7];
    const void* vb = d_in[8];

    int* flag = (int*)d_ws;
    ushort_t* arena = (ushort_t*)d_ws + 16;   // +32 B
    ushort_t* xb   = arena;                    // 8,388,608   (reused as ao_ws)
    ushort_t* peb  = arena + 8388608;          // 4,194,304 (4096 rows, last = junk)
    ushort_t* wqb  = arena + 12582912;
    ushort_t* wkb  = wqb + 1048576;
    ushort_t* wvb  = wkb + 1048576;
    ushort_t* wob  = wvb + 1048576;
    ushort_t* wpb  = wob + 1048576;
    ushort_t* ubb  = arena + 17825792;
    ushort_t* vbb  = ubb + 1024;
    ushort_t* q_ws  = arena + 17827840;
    ushort_t* k_ws  = q_ws + 8388608;
    ushort_t* vt_ws = k_ws + 8388608;          // [B,H,DK,T]
    ushort_t* p_ws  = vt_ws + 8388608;         // [H,PS_,DK]
    ushort_t* ao_ws = xb;                      // x dead after q/k/v GEMMs

    detect_kernel<<<1, 64, 0, stream>>>((const ushort_t*)x, flag);

    const int cvb = CV_TOT / 4 / 256;          // 17409 exact
    convert_kernel<0><<<cvb, 256, 0, stream>>>(flag, x, pe, Wq, Wk, Wv, Wo, Wp, ub, vb, arena);
    convert_kernel<1><<<cvb, 256, 0, stream>>>(flag, x, pe, Wq, Wk, Wv, Wo, Wp, ub, vb, arena);

    const dim3 gX(8, 64);   // N/128, M/128 for M=8192
    const dim3 gP(8, 32);   // M=4096 (padded)
    gemm_mfma<<<gX, 256, 0, stream>>>(flag, xb,  wqb, q_ws, 0);
    gemm_mfma<<<gX, 256, 0, stream>>>(flag, xb,  wkb, k_ws, 0);
    gemm_mfma<<<gX, 256, 0, stream>>>(flag, xb,  wvb, vt_ws, 2);
    gemm_mfma<<<gP, 256, 0, stream>>>(flag, peb, wpb, p_ws, 1);

    attn_mfma<<<dim3(T_ / 64, B_ * H_), 256, 0, stream>>>(
        q_ws, k_ws, vt_ws, p_ws, ubb, vbb, ao_ws);

    gemm_mfma<<<gX, 256, 0, stream>>>(flag, ao_ws, wob, d_out, 3);
    gemm_mfma<<<gX, 256, 0, stream>>>(flag, ao_ws, wob, d_out, 4);
}